// Round 10
// baseline (217.126 us; speedup 1.0000x reference)
//
#include <hip/hip_runtime.h>

constexpr int B = 128, C = 256;
constexpr float EPS = 1e-5f;
constexpr int NSG = B * 841;   // 107648 search GEMM columns
constexpr int NKG = B * 25;    // 3200 kernel GEMM columns

typedef unsigned short u16;
typedef short short8 __attribute__((ext_vector_type(8)));
typedef u16 u16x8 __attribute__((ext_vector_type(8)));
typedef float f32x4 __attribute__((ext_vector_type(4)));

__device__ __forceinline__ u16 bf16_rne(float x) {
    unsigned u = __builtin_bit_cast(unsigned, x);
    return (u16)((u + 0x7FFFu + ((u >> 16) & 1u)) >> 16);
}

#define GLOAD16(g, l)                                                              \
    __builtin_amdgcn_global_load_lds(                                              \
        (const __attribute__((address_space(1))) unsigned int*)(g),                \
        (__attribute__((address_space(3))) unsigned int*)(l), 16, 0, 0)

// ---------------------------------------------------------------------------
// wprep2: fp32 (C,C) -> frag-major hi/lo bf16 (A-frag of mfma_16x16x32 loads
// as one coalesced dwordx4 per lane). hi at [0,65536), lo at [65536,131072).
// ---------------------------------------------------------------------------
__global__ __launch_bounds__(256)
void wprep2(const float* __restrict__ ws, const float* __restrict__ wk,
            u16* __restrict__ WtS, u16* __restrict__ WtK) {
    int i = blockIdx.x * 256 + threadIdx.x;   // co*256 + k over 65536
    int co = i >> 8, k = i & 255;
    int t = k >> 5, cg = co >> 4;
    int lane = ((k >> 3) & 3) * 16 + (co & 15);
    int e = k & 7;
    size_t o = ((size_t)(t * 16 + cg) * 64 + lane) * 8 + e;
    {
        float a = ws[i];
        u16 h = bf16_rne(a);
        float hf = __builtin_bit_cast(float, (unsigned)h << 16);
        WtS[o] = h; WtS[65536 + o] = bf16_rne(a - hf);
    }
    {
        float a = wk[i];
        u16 h = bf16_rne(a);
        float hf = __builtin_bit_cast(float, (unsigned)h << 16);
        WtK[o] = h; WtK[65536 + o] = bf16_rne(a - hf);
    }
}

// ---------------------------------------------------------------------------
// dw_pass6 (search branch): depthwise 3x3 + BN1 + ReLU6 -> X3 planes,
// NO LDS transpose: thread task = (oh, 8-wide ow strip), loops CG=8 channels
// building u16x8 outputs channel-in-lane -> direct 16B stores in the plane
// layout [kc][n][8]. 128 thr/block, 116 tasks, S staged async (30.9KB LDS).
// ---------------------------------------------------------------------------
template<int IN_H, int CG>
__global__ __launch_bounds__(128)
void dw_pass6(const float* __restrict__ in, const float* __restrict__ dw_w,
              const float* __restrict__ bn1,
              u16* __restrict__ X3h, u16* __restrict__ X3l) {
    constexpr int OUT_H = IN_H - 2, ON = OUT_H * OUT_H, IHW = IN_H * IN_H;
    constexpr int NSTRIP = (OUT_H + 7) / 8;   // 4
    constexpr int NF4 = CG * IHW / 4;         // 1922
    constexpr int NSP = B * ON;
    __shared__ __align__(16) float S[CG * IHW + 16];   // +pad for strip over-read

    const int tid = threadIdx.x;
    const int b = blockIdx.x, g = blockIdx.y;
    const int ci0 = g * CG;
    const float* src = in + ((size_t)b * C + ci0) * IHW;

    // ---- async stage: contiguous 16B chunks
    #pragma unroll
    for (int ii = 0; ii < (NF4 + 127) / 128; ++ii) {
        int q = ii * 128 + tid;
        if (q < NF4) GLOAD16(src + q * 4, (char*)S + q * 16);
    }
    asm volatile("s_waitcnt vmcnt(0)" ::: "memory");
    __syncthreads();

    const int task = tid;
    if (task >= OUT_H * NSTRIP) return;
    const int oh = task / NSTRIP, s = task - oh * NSTRIP;
    const int ow0 = s * 8;

    u16x8 out_h[8], out_l[8];   // [o][cl]: channel-in-lane
    #pragma unroll
    for (int cl = 0; cl < CG; ++cl) {
        const int ci = ci0 + cl;
        float wreg[9];
        #pragma unroll
        for (int q = 0; q < 9; ++q) wreg[q] = dw_w[ci * 9 + q];   // uniform -> s_load
        const float inv = bn1[ci] * rsqrtf(bn1[3 * C + ci] + EPS);
        const float shv = bn1[C + ci] - bn1[2 * C + ci] * inv;
        float res[8] = {0.f, 0.f, 0.f, 0.f, 0.f, 0.f, 0.f, 0.f};
        #pragma unroll
        for (int dy = 0; dy < 3; ++dy) {
            const float* r = S + cl * IHW + (oh + dy) * IN_H + ow0;
            float x[10];
            #pragma unroll
            for (int j = 0; j < 10; ++j) x[j] = r[j];
            #pragma unroll
            for (int o = 0; o < 8; ++o)
                res[o] = fmaf(x[o], wreg[dy * 3],
                          fmaf(x[o + 1], wreg[dy * 3 + 1],
                           fmaf(x[o + 2], wreg[dy * 3 + 2], res[o])));
        }
        #pragma unroll
        for (int o = 0; o < 8; ++o) {
            float y = res[o] * inv + shv;
            y = fminf(fmaxf(y, 0.f), 6.f);
            u16 h = bf16_rne(y);
            float hf = __builtin_bit_cast(float, (unsigned)h << 16);
            out_h[o][cl] = h;
            out_l[o][cl] = bf16_rne(y - hf);
        }
    }

    // ---- direct plane stores: 16B per position, contiguous per thread
    const size_t nbase = (size_t)g * NSP + (size_t)b * ON + oh * OUT_H + ow0;
    u16* dh = X3h + nbase * 8;
    u16* dl = X3l + nbase * 8;
    #pragma unroll
    for (int o = 0; o < 8; ++o) {
        if (ow0 + o < OUT_H) {
            *(u16x8*)(dh + o * 8) = out_h[o];
            *(u16x8*)(dl + o * 8) = out_l[o];
        }
    }
}

// ---------------------------------------------------------------------------
// dw_pass4 (kernel branch, tiny): unchanged validated r8 version
// ---------------------------------------------------------------------------
template<int IN_H, int CG>
__global__ __launch_bounds__(256)
void dw_pass4(const float* __restrict__ in, const float* __restrict__ dw_w,
              const float* __restrict__ bn1,
              u16* __restrict__ X3h, u16* __restrict__ X3l) {
    constexpr int OUT_H = IN_H - 2, ON = OUT_H * OUT_H, IHW = IN_H * IN_H;
    constexpr int NSTRIP = (OUT_H + 7) / 8;
    constexpr int NFLT = CG * IHW;
    constexpr int NF4 = NFLT / 4;
    constexpr int SUBS = CG / 8;
    constexpr int NSP = B * ON;
    constexpr int PADC = CG + 2;
    constexpr unsigned SM_IN = (NFLT + 16) * 4;
    constexpr unsigned SM_XT = (unsigned)ON * PADC * 2;
    constexpr unsigned SMSZ = SM_IN > SM_XT ? SM_IN : SM_XT;
    __shared__ __align__(16) char SMEM[SMSZ];
    float* S = (float*)SMEM;
    u16* xt = (u16*)SMEM;

    const int tid = threadIdx.x;
    const int b = blockIdx.x, g = blockIdx.y;
    const int ci0 = g * CG;
    const float* src = in + ((size_t)b * C + ci0) * IHW;

    for (int q = tid; q < NF4; q += 256)
        ((float4*)S)[q] = ((const float4*)src)[q];
    __syncthreads();

    const bool active = tid < CG * OUT_H;
    int cl = 0, oh = 0;
    if (active) { cl = tid / OUT_H; oh = tid - cl * OUT_H; }
    unsigned outv[NSTRIP][8];
    if (active) {
        const int ci = ci0 + cl;
        float wreg[9];
        #pragma unroll
        for (int q = 0; q < 9; ++q) wreg[q] = dw_w[ci * 9 + q];
        const float inv = bn1[ci] * rsqrtf(bn1[3 * C + ci] + EPS);
        const float shv = bn1[C + ci] - bn1[2 * C + ci] * inv;
        #pragma unroll
        for (int s = 0; s < NSTRIP; ++s) {
            float res[8] = {0.f, 0.f, 0.f, 0.f, 0.f, 0.f, 0.f, 0.f};
            #pragma unroll
            for (int dy = 0; dy < 3; ++dy) {
                const float* r = S + cl * IHW + (oh + dy) * IN_H + s * 8;
                float x[10];
                #pragma unroll
                for (int j = 0; j < 10; ++j) x[j] = r[j];
                #pragma unroll
                for (int o = 0; o < 8; ++o)
                    res[o] = fmaf(x[o], wreg[dy * 3],
                              fmaf(x[o + 1], wreg[dy * 3 + 1],
                               fmaf(x[o + 2], wreg[dy * 3 + 2], res[o])));
            }
            #pragma unroll
            for (int o = 0; o < 8; ++o) {
                float y = res[o] * inv + shv;
                y = fminf(fmaxf(y, 0.f), 6.f);
                u16 h = bf16_rne(y);
                float hf = __builtin_bit_cast(float, (unsigned)h << 16);
                outv[s][o] = (unsigned)h | ((unsigned)bf16_rne(y - hf) << 16);
            }
        }
    }
    __syncthreads();

    #pragma unroll
    for (int plane = 0; plane < 2; ++plane) {
        if (active) {
            #pragma unroll
            for (int s = 0; s < NSTRIP; ++s) {
                const int ow0 = s * 8;
                #pragma unroll
                for (int o = 0; o < 8; ++o) {
                    if (ow0 + o < OUT_H) {
                        int n = oh * OUT_H + ow0 + o;
                        xt[n * PADC + cl] = plane ? (u16)(outv[s][o] >> 16)
                                                  : (u16)outv[s][o];
                    }
                }
            }
        }
        __syncthreads();
        for (int q = tid; q < ON * SUBS; q += 256) {
            int sub = q / ON, n = q - sub * ON;
            const unsigned* w = (const unsigned*)xt + n * (PADC / 2) + sub * 4;
            uint4 v = {w[0], w[1], w[2], w[3]};
            u16* dst = (plane ? X3l : X3h) +
                       ((size_t)(g * SUBS + sub) * NSP + (size_t)b * ON + n) * 8;
            *(uint4*)dst = v;
        }
        if (plane == 0) __syncthreads();
    }
}

// ---------------------------------------------------------------------------
// gemm4 (r7-validated): LDS-free, barrier-free MFMA GEMM, direct frags.
// ---------------------------------------------------------------------------
template<int PQ>
__global__ __launch_bounds__(256)
void gemm4(const u16* __restrict__ X3h, const u16* __restrict__ X3l,
           const u16* __restrict__ Wt, const float* __restrict__ pw_b,
           const float* __restrict__ bn2, float* __restrict__ out) {
    constexpr int NSP = B * PQ;
    const int lane = threadIdx.x & 63, wave = threadIdx.x >> 6;
    const int lh = lane >> 4, ll = lane & 15;
    const int n0 = blockIdx.x * 64;
    const u16* Wth = Wt;
    const u16* Wtl = Wt + 65536;

    f32x4 acc[4][4] = {};

    #pragma unroll 1
    for (int t = 0; t < 8; ++t) {
        short8 awh[4], awl[4], bxh[4], bxl[4];
        #pragma unroll
        for (int j = 0; j < 4; ++j) {
            size_t off = ((size_t)(t * 4 + lh) * NSP + n0 + j * 16 + ll) * 8;
            bxh[j] = *(const short8*)(X3h + off);
            bxl[j] = *(const short8*)(X3l + off);
        }
        #pragma unroll
        for (int i = 0; i < 4; ++i) {
            int cg = wave * 4 + i;
            size_t off = ((size_t)(t * 16 + cg) * 64 + lane) * 8;
            awh[i] = *(const short8*)(Wth + off);
            awl[i] = *(const short8*)(Wtl + off);
        }
        #pragma unroll
        for (int i = 0; i < 4; ++i)
            #pragma unroll
            for (int j = 0; j < 4; ++j) {
                acc[i][j] = __builtin_amdgcn_mfma_f32_16x16x32_bf16(awh[i], bxh[j], acc[i][j], 0, 0, 0);
                acc[i][j] = __builtin_amdgcn_mfma_f32_16x16x32_bf16(awh[i], bxl[j], acc[i][j], 0, 0, 0);
                acc[i][j] = __builtin_amdgcn_mfma_f32_16x16x32_bf16(awl[i], bxh[j], acc[i][j], 0, 0, 0);
            }
    }

    int bj[4], pj[4];
    #pragma unroll
    for (int j = 0; j < 4; ++j) {
        int nn = n0 + j * 16 + ll;
        bj[j] = nn / PQ; pj[j] = nn - bj[j] * PQ;
    }
    #pragma unroll
    for (int i = 0; i < 4; ++i) {
        #pragma unroll
        for (int r = 0; r < 4; ++r) {
            int co = wave * 64 + i * 16 + lh * 4 + r;
            float inv = bn2[co] * rsqrtf(bn2[3 * C + co] + EPS);
            float sh  = bn2[C + co] - bn2[2 * C + co] * inv + pw_b[co] * inv;
            #pragma unroll
            for (int j = 0; j < 4; ++j)
                out[((size_t)bj[j] * C + co) * PQ + pj[j]] = acc[i][j][r] * inv + sh;
        }
    }
}

// ---------------------------------------------------------------------------
// xcorr: 10 (b,c) pairs per block; 25 threads/pair, 5x5 output tile each
// ---------------------------------------------------------------------------
__global__ __launch_bounds__(256)
void xcorr2(const float* __restrict__ s, const float* __restrict__ k,
            float* __restrict__ out) {
    const int bc0 = blockIdx.x * 10;
    const int nbc = min(10, B * C - bc0);
    __shared__ float ss[10 * 841];
    __shared__ float ks[10 * 25];
    const int tid = threadIdx.x;
    for (int i = tid; i < nbc * 841; i += 256) ss[i] = s[(size_t)bc0 * 841 + i];
    for (int i = tid; i < nbc * 25; i += 256) ks[i] = k[(size_t)bc0 * 25 + i];
    __syncthreads();

    const int lb = tid / 25, lt = tid - lb * 25;
    if (lb >= nbc) return;
    const int ohg = lt / 5, owg = lt - ohg * 5;
    const float* sp = ss + lb * 841 + (ohg * 5) * 29 + owg * 5;
    float kk[25];
    #pragma unroll
    for (int q = 0; q < 25; ++q) kk[q] = ks[lb * 25 + q];

    float acc[5][5] = {};
    #pragma unroll
    for (int ir = 0; ir < 9; ++ir) {
        float row[9];
        #pragma unroll
        for (int j = 0; j < 9; ++j) row[j] = sp[ir * 29 + j];
        #pragma unroll
        for (int oi = 0; oi < 5; ++oi) {
            int ki = ir - oi;
            if (ki < 0 || ki > 4) continue;
            #pragma unroll
            for (int oj = 0; oj < 5; ++oj)
                #pragma unroll
                for (int kj = 0; kj < 5; ++kj)
                    acc[oi][oj] = fmaf(row[oj + kj], kk[ki * 5 + kj], acc[oi][oj]);
        }
    }
    float* op = out + (size_t)(bc0 + lb) * 625;
    #pragma unroll
    for (int oi = 0; oi < 5; ++oi)
        #pragma unroll
        for (int oj = 0; oj < 5; ++oj)
            op[(ohg * 5 + oi) * 25 + owg * 5 + oj] = acc[oi][oj];
}

// ---------------------------------------------------------------------------
// Fallback (round-1 fp32 path) in case ws_size is too small
// ---------------------------------------------------------------------------
template<int IN_H>
__global__ __launch_bounds__(256)
void branch_fallback(const float* __restrict__ in, const float* __restrict__ dw_w,
                     const float* __restrict__ bn1, const float* __restrict__ pw_w,
                     const float* __restrict__ pw_b, const float* __restrict__ bn2,
                     float* __restrict__ out) {
    constexpr int OUT_H = IN_H - 2;
    constexpr int P = OUT_H * OUT_H;
    const int n0  = blockIdx.x * 64;
    const int co0 = blockIdx.y * 64;
    const int tid = threadIdx.x;
    const int tx = tid & 15, ty = tid >> 4;
    __shared__ __align__(16) float Ws[16][64];
    __shared__ __align__(16) float Xs2[16][64];
    float acc[4][4] = {};
    for (int k0 = 0; k0 < C; k0 += 16) {
        #pragma unroll
        for (int e = 0; e < 4; e++) {
            int idx = e * 256 + tid;
            int m = idx & 63, kk = idx >> 6;
            Ws[kk][m] = pw_w[(co0 + m) * C + (k0 + kk)];
        }
        #pragma unroll
        for (int e = 0; e < 4; e++) {
            int idx = e * 256 + tid;
            int nn = idx & 63, kk = idx >> 6;
            int ci = k0 + kk;
            int n = n0 + nn;
            int b = n / P, p = n - b * P;
            int oh = p / OUT_H, ow = p - oh * OUT_H;
            const float* ip = in + (((size_t)b * C + ci) * IN_H + oh) * IN_H + ow;
            const float* wp = dw_w + ci * 9;
            float s = 0.f;
            #pragma unroll
            for (int dy = 0; dy < 3; dy++)
                #pragma unroll
                for (int dx = 0; dx < 3; dx++)
                    s = fmaf(ip[dy * IN_H + dx], wp[dy * 3 + dx], s);
            float inv = bn1[ci] * rsqrtf(bn1[3 * C + ci] + EPS);
            float y = s * inv + (bn1[C + ci] - bn1[2 * C + ci] * inv);
            Xs2[kk][nn] = fminf(fmaxf(y, 0.f), 6.f);
        }
        __syncthreads();
        #pragma unroll
        for (int kk = 0; kk < 16; kk++) {
            float4 av = *reinterpret_cast<const float4*>(&Ws[kk][ty * 4]);
            float4 bv = *reinterpret_cast<const float4*>(&Xs2[kk][tx * 4]);
            float a[4] = {av.x, av.y, av.z, av.w};
            float bb[4] = {bv.x, bv.y, bv.z, bv.w};
            #pragma unroll
            for (int i = 0; i < 4; i++)
                #pragma unroll
                for (int j = 0; j < 4; j++)
                    acc[i][j] = fmaf(a[i], bb[j], acc[i][j]);
        }
        __syncthreads();
    }
    #pragma unroll
    for (int i = 0; i < 4; i++) {
        int co = co0 + ty * 4 + i;
        float inv = bn2[co] * rsqrtf(bn2[3 * C + co] + EPS);
        float sh  = (bn2[C + co] - bn2[2 * C + co] * inv) + pw_b[co] * inv;
        int n = n0 + tx * 4;
        #pragma unroll
        for (int j = 0; j < 4; j++) {
            int nj = n + j;
            int bj2 = nj / P, pj2 = nj - bj2 * P;
            out[((size_t)bj2 * C + co) * P + pj2] = acc[i][j] * inv + sh;
        }
    }
}

extern "C" void kernel_launch(void* const* d_in, const int* in_sizes, int n_in,
                              void* d_out, int out_size, void* d_ws, size_t ws_size,
                              hipStream_t stream) {
    const float* kernel = (const float*)d_in[0];
    const float* search = (const float*)d_in[1];
    const float* k_dw_w = (const float*)d_in[2];
    const float* k_bn1  = (const float*)d_in[3];
    const float* k_pw_w = (const float*)d_in[4];
    const float* k_pw_b = (const float*)d_in[5];
    const float* k_bn2  = (const float*)d_in[6];
    const float* s_dw_w = (const float*)d_in[7];
    const float* s_bn1  = (const float*)d_in[8];
    const float* s_pw_w = (const float*)d_in[9];
    const float* s_pw_b = (const float*)d_in[10];
    const float* s_bn2  = (const float*)d_in[11];

    constexpr size_t SB_B  = (size_t)NSG * C * 4;      // 110,231,552
    constexpr size_t KB_B  = (size_t)NKG * C * 4;      //   3,276,800
    constexpr size_t X3S_B = (size_t)NSG * 512;        //  55,115,776 per plane
    constexpr size_t X3K_B = (size_t)NKG * 512;        //   1,638,400 per plane
    constexpr size_t W_B   = (size_t)131072 * 2;       //     262,144 (hi+lo frag-major)
    constexpr size_t NEED  = SB_B + KB_B + 2 * X3S_B + 2 * X3K_B + 2 * W_B;

    if (ws_size >= NEED) {
        char* base = (char*)d_ws;
        float* Sb  = (float*)base;  base += SB_B;
        float* Kb  = (float*)base;  base += KB_B;
        u16* X3hs  = (u16*)base;    base += X3S_B;
        u16* X3ls  = (u16*)base;    base += X3S_B;
        u16* X3hk  = (u16*)base;    base += X3K_B;
        u16* X3lk  = (u16*)base;    base += X3K_B;
        u16* WtS   = (u16*)base;    base += W_B;
        u16* WtK   = (u16*)base;

        wprep2<<<dim3(256), dim3(256), 0, stream>>>(s_pw_w, k_pw_w, WtS, WtK);
        dw_pass6<31, 8><<<dim3(B, 32), dim3(128), 0, stream>>>(search, s_dw_w, s_bn1, X3hs, X3ls);
        dw_pass4<7, 32><<<dim3(B, 8), dim3(256), 0, stream>>>(kernel, k_dw_w, k_bn1, X3hk, X3lk);
        gemm4<841><<<dim3(NSG / 64), dim3(256), 0, stream>>>(X3hs, X3ls, WtS, s_pw_b, s_bn2, Sb);
        gemm4<25><<<dim3(NKG / 64), dim3(256), 0, stream>>>(X3hk, X3lk, WtK, k_pw_b, k_bn2, Kb);
        xcorr2<<<dim3((B * C + 9) / 10), dim3(256), 0, stream>>>(Sb, Kb, (float*)d_out);
    } else {
        float* s_buf = (float*)d_ws;
        float* k_buf = s_buf + (size_t)B * C * 29 * 29;
        branch_fallback<7><<<dim3(50, 4), dim3(256), 0, stream>>>(
            kernel, k_dw_w, k_bn1, k_pw_w, k_pw_b, k_bn2, k_buf);
        branch_fallback<31><<<dim3(1682, 4), dim3(256), 0, stream>>>(
            search, s_dw_w, s_bn1, s_pw_w, s_pw_b, s_bn2, s_buf);
        xcorr2<<<dim3((B * C + 9) / 10), dim3(256), 0, stream>>>(s_buf, k_buf, (float*)d_out);
    }
}

// Round 11
// 148.310 us; speedup vs baseline: 1.4640x; 1.4640x over previous
//
#include <hip/hip_runtime.h>

constexpr int B = 128, C = 256;
constexpr float EPS = 1e-5f;
constexpr int NSG = B * 841;   // 107648 search GEMM columns
constexpr int NKG = B * 25;    // 3200 kernel GEMM columns

typedef unsigned short u16;
typedef short short8 __attribute__((ext_vector_type(8)));
typedef u16 u16x8 __attribute__((ext_vector_type(8)));
typedef float f32x4 __attribute__((ext_vector_type(4)));

__device__ __forceinline__ u16 bf16_rne(float x) {
    unsigned u = __builtin_bit_cast(unsigned, x);
    return (u16)((u + 0x7FFFu + ((u >> 16) & 1u)) >> 16);
}
__device__ __forceinline__ float bf16_f(u16 h) {
    return __builtin_bit_cast(float, (unsigned)h << 16);
}

// ---------------------------------------------------------------------------
// wprep3: fp32 (C,C) -> frag-major bf16 (single plane).
// Wt[(t*16+cg)*64 + lane][8]: lane l -> co = cg*16+(l&15), k = t*32+(l>>4)*8+e.
// ---------------------------------------------------------------------------
__global__ __launch_bounds__(256)
void wprep3(const float* __restrict__ ws, const float* __restrict__ wk,
            u16* __restrict__ WtS, u16* __restrict__ WtK) {
    int i = blockIdx.x * 256 + threadIdx.x;   // co*256 + k over 65536
    int co = i >> 8, k = i & 255;
    int t = k >> 5, cg = co >> 4;
    int lane = ((k >> 3) & 3) * 16 + (co & 15);
    int e = k & 7;
    size_t o = ((size_t)(t * 16 + cg) * 64 + lane) * 8 + e;
    WtS[o] = bf16_rne(ws[i]);
    WtK[o] = bf16_rne(wk[i]);
}

// ---------------------------------------------------------------------------
// dw_pass7: depthwise 3x3 + BN1 + ReLU6 -> single bf16 plane X3[kc][n][8].
// r8-validated structure (stage / compute / padded-LDS scatter / coalesced
// write), single plane -> half the scatter+write+cvt work of dw_pass4.
// ---------------------------------------------------------------------------
template<int IN_H, int CG>
__global__ __launch_bounds__(256)
void dw_pass7(const float* __restrict__ in, const float* __restrict__ dw_w,
              const float* __restrict__ bn1, u16* __restrict__ X3) {
    constexpr int OUT_H = IN_H - 2, ON = OUT_H * OUT_H, IHW = IN_H * IN_H;
    constexpr int NSTRIP = (OUT_H + 7) / 8;
    constexpr int NFLT = CG * IHW;
    constexpr int NF4 = NFLT / 4;
    constexpr int SUBS = CG / 8;
    constexpr int NSP = B * ON;
    constexpr int PADC = CG + 2;
    constexpr unsigned SM_IN = (NFLT + 16) * 4;
    constexpr unsigned SM_XT = (unsigned)ON * PADC * 2;
    constexpr unsigned SMSZ = SM_IN > SM_XT ? SM_IN : SM_XT;
    __shared__ __align__(16) char SMEM[SMSZ];
    float* S = (float*)SMEM;
    u16* xt = (u16*)SMEM;

    const int tid = threadIdx.x;
    const int b = blockIdx.x, g = blockIdx.y;
    const int ci0 = g * CG;
    const float* src = in + ((size_t)b * C + ci0) * IHW;

    for (int q = tid; q < NF4; q += 256)
        ((float4*)S)[q] = ((const float4*)src)[q];
    __syncthreads();

    const bool active = tid < CG * OUT_H;
    int cl = 0, oh = 0;
    if (active) { cl = tid / OUT_H; oh = tid - cl * OUT_H; }
    u16 outv[NSTRIP][8];
    if (active) {
        const int ci = ci0 + cl;
        float wreg[9];
        #pragma unroll
        for (int q = 0; q < 9; ++q) wreg[q] = dw_w[ci * 9 + q];
        const float inv = bn1[ci] * rsqrtf(bn1[3 * C + ci] + EPS);
        const float shv = bn1[C + ci] - bn1[2 * C + ci] * inv;
        #pragma unroll
        for (int s = 0; s < NSTRIP; ++s) {
            float res[8] = {0.f, 0.f, 0.f, 0.f, 0.f, 0.f, 0.f, 0.f};
            #pragma unroll
            for (int dy = 0; dy < 3; ++dy) {
                const float* r = S + cl * IHW + (oh + dy) * IN_H + s * 8;
                float x[10];
                #pragma unroll
                for (int j = 0; j < 10; ++j) x[j] = r[j];
                #pragma unroll
                for (int o = 0; o < 8; ++o)
                    res[o] = fmaf(x[o], wreg[dy * 3],
                              fmaf(x[o + 1], wreg[dy * 3 + 1],
                               fmaf(x[o + 2], wreg[dy * 3 + 2], res[o])));
            }
            #pragma unroll
            for (int o = 0; o < 8; ++o) {
                float y = res[o] * inv + shv;
                y = fminf(fmaxf(y, 0.f), 6.f);
                outv[s][o] = bf16_rne(y);
            }
        }
    }
    __syncthreads();   // all S reads complete; xt may overwrite

    if (active) {
        #pragma unroll
        for (int s = 0; s < NSTRIP; ++s) {
            const int ow0 = s * 8;
            #pragma unroll
            for (int o = 0; o < 8; ++o) {
                if (ow0 + o < OUT_H) {
                    int n = oh * OUT_H + ow0 + o;
                    xt[n * PADC + cl] = outv[s][o];
                }
            }
        }
    }
    __syncthreads();

    for (int q = tid; q < ON * SUBS; q += 256) {
        int sub = q / ON, n = q - sub * ON;
        const unsigned* w = (const unsigned*)xt + n * (PADC / 2) + sub * 4;
        uint4 v = {w[0], w[1], w[2], w[3]};
        u16* dst = X3 + ((size_t)(g * SUBS + sub) * NSP + (size_t)b * ON + n) * 8;
        *(uint4*)dst = v;
    }
}

// ---------------------------------------------------------------------------
// gemm6: LDS-free, barrier-free bf16 MFMA GEMM (r7-validated structure,
// single product), bf16 output with fused bias+BN2.
// ---------------------------------------------------------------------------
template<int PQ>
__global__ __launch_bounds__(256)
void gemm6(const u16* __restrict__ X3, const u16* __restrict__ Wt,
           const float* __restrict__ pw_b, const float* __restrict__ bn2,
           u16* __restrict__ out) {
    constexpr int NSP = B * PQ;
    const int lane = threadIdx.x & 63, wave = threadIdx.x >> 6;
    const int lh = lane >> 4, ll = lane & 15;
    const int n0 = blockIdx.x * 64;

    f32x4 acc[4][4] = {};

    #pragma unroll 1
    for (int t = 0; t < 8; ++t) {
        short8 aw[4], bx[4];
        #pragma unroll
        for (int j = 0; j < 4; ++j) {
            size_t off = ((size_t)(t * 4 + lh) * NSP + n0 + j * 16 + ll) * 8;
            bx[j] = *(const short8*)(X3 + off);
        }
        #pragma unroll
        for (int i = 0; i < 4; ++i) {
            int cg = wave * 4 + i;
            size_t off = ((size_t)(t * 16 + cg) * 64 + lane) * 8;
            aw[i] = *(const short8*)(Wt + off);
        }
        #pragma unroll
        for (int i = 0; i < 4; ++i)
            #pragma unroll
            for (int j = 0; j < 4; ++j)
                acc[i][j] = __builtin_amdgcn_mfma_f32_16x16x32_bf16(aw[i], bx[j], acc[i][j], 0, 0, 0);
    }

    int bj[4], pj[4];
    #pragma unroll
    for (int j = 0; j < 4; ++j) {
        int nn = n0 + j * 16 + ll;
        bj[j] = nn / PQ; pj[j] = nn - bj[j] * PQ;
    }
    #pragma unroll
    for (int i = 0; i < 4; ++i) {
        #pragma unroll
        for (int r = 0; r < 4; ++r) {
            int co = wave * 64 + i * 16 + lh * 4 + r;
            float inv = bn2[co] * rsqrtf(bn2[3 * C + co] + EPS);
            float sh  = bn2[C + co] - bn2[2 * C + co] * inv + pw_b[co] * inv;
            #pragma unroll
            for (int j = 0; j < 4; ++j)
                out[((size_t)bj[j] * C + co) * PQ + pj[j]] = bf16_rne(acc[i][j][r] * inv + sh);
        }
    }
}

// ---------------------------------------------------------------------------
// xcorr3: bf16 inputs, fp32 output. 10 (b,c) pairs per block; 25 threads/pair,
// 5x5 output tile each (r4-validated compute).
// ---------------------------------------------------------------------------
__global__ __launch_bounds__(256)
void xcorr3(const u16* __restrict__ s, const u16* __restrict__ k,
            float* __restrict__ out) {
    const int bc0 = blockIdx.x * 10;
    const int nbc = min(10, B * C - bc0);
    __shared__ float ss[10 * 841];
    __shared__ float ks[10 * 25];
    const int tid = threadIdx.x;
    for (int i = tid; i < nbc * 841; i += 256) ss[i] = bf16_f(s[(size_t)bc0 * 841 + i]);
    for (int i = tid; i < nbc * 25; i += 256) ks[i] = bf16_f(k[(size_t)bc0 * 25 + i]);
    __syncthreads();

    const int lb = tid / 25, lt = tid - lb * 25;
    if (lb >= nbc) return;
    const int ohg = lt / 5, owg = lt - ohg * 5;
    const float* sp = ss + lb * 841 + (ohg * 5) * 29 + owg * 5;
    float kk[25];
    #pragma unroll
    for (int q = 0; q < 25; ++q) kk[q] = ks[lb * 25 + q];

    float acc[5][5] = {};
    #pragma unroll
    for (int ir = 0; ir < 9; ++ir) {
        float row[9];
        #pragma unroll
        for (int j = 0; j < 9; ++j) row[j] = sp[ir * 29 + j];
        #pragma unroll
        for (int oi = 0; oi < 5; ++oi) {
            int ki = ir - oi;
            if (ki < 0 || ki > 4) continue;
            #pragma unroll
            for (int oj = 0; oj < 5; ++oj)
                #pragma unroll
                for (int kj = 0; kj < 5; ++kj)
                    acc[oi][oj] = fmaf(row[oj + kj], kk[ki * 5 + kj], acc[oi][oj]);
        }
    }
    float* op = out + (size_t)(bc0 + lb) * 625;
    #pragma unroll
    for (int oi = 0; oi < 5; ++oi)
        #pragma unroll
        for (int oj = 0; oj < 5; ++oj)
            op[(ohg * 5 + oi) * 25 + owg * 5 + oj] = acc[oi][oj];
}

// ---------------------------------------------------------------------------
// Fallback (round-1 fp32 path) in case ws_size is too small
// ---------------------------------------------------------------------------
template<int IN_H>
__global__ __launch_bounds__(256)
void branch_fallback(const float* __restrict__ in, const float* __restrict__ dw_w,
                     const float* __restrict__ bn1, const float* __restrict__ pw_w,
                     const float* __restrict__ pw_b, const float* __restrict__ bn2,
                     float* __restrict__ out) {
    constexpr int OUT_H = IN_H - 2;
    constexpr int P = OUT_H * OUT_H;
    const int n0  = blockIdx.x * 64;
    const int co0 = blockIdx.y * 64;
    const int tid = threadIdx.x;
    const int tx = tid & 15, ty = tid >> 4;
    __shared__ __align__(16) float Ws[16][64];
    __shared__ __align__(16) float Xs2[16][64];
    float acc[4][4] = {};
    for (int k0 = 0; k0 < C; k0 += 16) {
        #pragma unroll
        for (int e = 0; e < 4; e++) {
            int idx = e * 256 + tid;
            int m = idx & 63, kk = idx >> 6;
            Ws[kk][m] = pw_w[(co0 + m) * C + (k0 + kk)];
        }
        #pragma unroll
        for (int e = 0; e < 4; e++) {
            int idx = e * 256 + tid;
            int nn = idx & 63, kk = idx >> 6;
            int ci = k0 + kk;
            int n = n0 + nn;
            int b = n / P, p = n - b * P;
            int oh = p / OUT_H, ow = p - oh * OUT_H;
            const float* ip = in + (((size_t)b * C + ci) * IN_H + oh) * IN_H + ow;
            const float* wp = dw_w + ci * 9;
            float s = 0.f;
            #pragma unroll
            for (int dy = 0; dy < 3; dy++)
                #pragma unroll
                for (int dx = 0; dx < 3; dx++)
                    s = fmaf(ip[dy * IN_H + dx], wp[dy * 3 + dx], s);
            float inv = bn1[ci] * rsqrtf(bn1[3 * C + ci] + EPS);
            float y = s * inv + (bn1[C + ci] - bn1[2 * C + ci] * inv);
            Xs2[kk][nn] = fminf(fmaxf(y, 0.f), 6.f);
        }
        __syncthreads();
        #pragma unroll
        for (int kk = 0; kk < 16; kk++) {
            float4 av = *reinterpret_cast<const float4*>(&Ws[kk][ty * 4]);
            float4 bv = *reinterpret_cast<const float4*>(&Xs2[kk][tx * 4]);
            float a[4] = {av.x, av.y, av.z, av.w};
            float bb[4] = {bv.x, bv.y, bv.z, bv.w};
            #pragma unroll
            for (int i = 0; i < 4; i++)
                #pragma unroll
                for (int j = 0; j < 4; j++)
                    acc[i][j] = fmaf(a[i], bb[j], acc[i][j]);
        }
        __syncthreads();
    }
    #pragma unroll
    for (int i = 0; i < 4; i++) {
        int co = co0 + ty * 4 + i;
        float inv = bn2[co] * rsqrtf(bn2[3 * C + co] + EPS);
        float sh  = (bn2[C + co] - bn2[2 * C + co] * inv) + pw_b[co] * inv;
        int n = n0 + tx * 4;
        #pragma unroll
        for (int j = 0; j < 4; j++) {
            int nj = n + j;
            int bj2 = nj / P, pj2 = nj - bj2 * P;
            out[((size_t)bj2 * C + co) * P + pj2] = acc[i][j] * inv + sh;
        }
    }
}

__global__ __launch_bounds__(256)
void xcorr2f(const float* __restrict__ s, const float* __restrict__ k,
             float* __restrict__ out) {
    const int bc0 = blockIdx.x * 10;
    const int nbc = min(10, B * C - bc0);
    __shared__ float ss[10 * 841];
    __shared__ float ks[10 * 25];
    const int tid = threadIdx.x;
    for (int i = tid; i < nbc * 841; i += 256) ss[i] = s[(size_t)bc0 * 841 + i];
    for (int i = tid; i < nbc * 25; i += 256) ks[i] = k[(size_t)bc0 * 25 + i];
    __syncthreads();
    const int lb = tid / 25, lt = tid - lb * 25;
    if (lb >= nbc) return;
    const int ohg = lt / 5, owg = lt - ohg * 5;
    const float* sp = ss + lb * 841 + (ohg * 5) * 29 + owg * 5;
    float kk[25];
    #pragma unroll
    for (int q = 0; q < 25; ++q) kk[q] = ks[lb * 25 + q];
    float acc[5][5] = {};
    #pragma unroll
    for (int ir = 0; ir < 9; ++ir) {
        float row[9];
        #pragma unroll
        for (int j = 0; j < 9; ++j) row[j] = sp[ir * 29 + j];
        #pragma unroll
        for (int oi = 0; oi < 5; ++oi) {
            int ki = ir - oi;
            if (ki < 0 || ki > 4) continue;
            #pragma unroll
            for (int oj = 0; oj < 5; ++oj)
                #pragma unroll
                for (int kj = 0; kj < 5; ++kj)
                    acc[oi][oj] = fmaf(row[oj + kj], kk[ki * 5 + kj], acc[oi][oj]);
        }
    }
    float* op = out + (size_t)(bc0 + lb) * 625;
    #pragma unroll
    for (int oi = 0; oi < 5; ++oi)
        #pragma unroll
        for (int oj = 0; oj < 5; ++oj)
            op[(ohg * 5 + oi) * 25 + owg * 5 + oj] = acc[oi][oj];
}

extern "C" void kernel_launch(void* const* d_in, const int* in_sizes, int n_in,
                              void* d_out, int out_size, void* d_ws, size_t ws_size,
                              hipStream_t stream) {
    const float* kernel = (const float*)d_in[0];
    const float* search = (const float*)d_in[1];
    const float* k_dw_w = (const float*)d_in[2];
    const float* k_bn1  = (const float*)d_in[3];
    const float* k_pw_w = (const float*)d_in[4];
    const float* k_pw_b = (const float*)d_in[5];
    const float* k_bn2  = (const float*)d_in[6];
    const float* s_dw_w = (const float*)d_in[7];
    const float* s_bn1  = (const float*)d_in[8];
    const float* s_pw_w = (const float*)d_in[9];
    const float* s_pw_b = (const float*)d_in[10];
    const float* s_bn2  = (const float*)d_in[11];

    constexpr size_t SB_B  = (size_t)NSG * C * 2;      // 55,115,776 (bf16)
    constexpr size_t KB_B  = (size_t)NKG * C * 2;      //  1,638,400
    constexpr size_t X3S_B = (size_t)NSG * 256;        // 27,557,888... (NSG*C*2? see below)
    // X3 plane bytes = NSG * C * 2 (C channels, 2B each) = NSG*512 for hi+lo before;
    // single plane: NSG * C * 2 / ... keep explicit:
    constexpr size_t X3S_BB = (size_t)NSG * C * 2;     // 55,115,776
    constexpr size_t X3K_BB = (size_t)NKG * C * 2;     //  1,638,400
    constexpr size_t W_B    = (size_t)C * C * 2;       //    131,072 per branch
    constexpr size_t NEED   = SB_B + KB_B + X3S_BB + X3K_BB + 2 * W_B;

    if (ws_size >= NEED) {
        char* base = (char*)d_ws;
        u16* Sb   = (u16*)base;   base += SB_B;
        u16* Kb   = (u16*)base;   base += KB_B;
        u16* X3s  = (u16*)base;   base += X3S_BB;
        u16* X3k  = (u16*)base;   base += X3K_BB;
        u16* WtS  = (u16*)base;   base += W_B;
        u16* WtK  = (u16*)base;

        wprep3<<<dim3(256), dim3(256), 0, stream>>>(s_pw_w, k_pw_w, WtS, WtK);
        dw_pass7<31, 8><<<dim3(B, 32), dim3(256), 0, stream>>>(search, s_dw_w, s_bn1, X3s);
        dw_pass7<7, 32><<<dim3(B, 8), dim3(256), 0, stream>>>(kernel, k_dw_w, k_bn1, X3k);
        gemm6<841><<<dim3(NSG / 64), dim3(256), 0, stream>>>(X3s, WtS, s_pw_b, s_bn2, Sb);
        gemm6<25><<<dim3(NKG / 64), dim3(256), 0, stream>>>(X3k, WtK, k_pw_b, k_bn2, Kb);
        xcorr3<<<dim3((B * C + 9) / 10), dim3(256), 0, stream>>>(Sb, Kb, (float*)d_out);
    } else {
        float* s_buf = (float*)d_ws;
        float* k_buf = s_buf + (size_t)B * C * 29 * 29;
        branch_fallback<7><<<dim3(50, 4), dim3(256), 0, stream>>>(
            kernel, k_dw_w, k_bn1, k_pw_w, k_pw_b, k_bn2, k_buf);
        branch_fallback<31><<<dim3(1682, 4), dim3(256), 0, stream>>>(
            search, s_dw_w, s_bn1, s_pw_w, s_pw_b, s_bn2, s_buf);
        xcorr2f<<<dim3((B * C + 9) / 10), dim3(256), 0, stream>>>(s_buf, k_buf, (float*)d_out);
    }
}

// Round 12
// 142.554 us; speedup vs baseline: 1.5231x; 1.0404x over previous
//
#include <hip/hip_runtime.h>

constexpr int B = 128, C = 256;
constexpr float EPS = 1e-5f;
constexpr int NSG = B * 841;   // 107648 search GEMM columns
constexpr int NKG = B * 25;    // 3200 kernel GEMM columns

typedef unsigned short u16;
typedef short short8 __attribute__((ext_vector_type(8)));
typedef u16 u16x8 __attribute__((ext_vector_type(8)));
typedef float f32x4 __attribute__((ext_vector_type(4)));

__device__ __forceinline__ u16 bf16_rne(float x) {
    unsigned u = __builtin_bit_cast(unsigned, x);
    return (u16)((u + 0x7FFFu + ((u >> 16) & 1u)) >> 16);
}
__device__ __forceinline__ float bf16_f(u16 h) {
    return __builtin_bit_cast(float, (unsigned)h << 16);
}

#define GLOAD16(g, l)                                                              \
    __builtin_amdgcn_global_load_lds(                                              \
        (const __attribute__((address_space(1))) unsigned int*)(g),                \
        (__attribute__((address_space(3))) unsigned int*)(l), 16, 0, 0)

// ---------------------------------------------------------------------------
// wprep3: fp32 (C,C) -> frag-major bf16 (single plane).
// ---------------------------------------------------------------------------
__global__ __launch_bounds__(256)
void wprep3(const float* __restrict__ ws, const float* __restrict__ wk,
            u16* __restrict__ WtS, u16* __restrict__ WtK) {
    int i = blockIdx.x * 256 + threadIdx.x;   // co*256 + k over 65536
    int co = i >> 8, k = i & 255;
    int t = k >> 5, cg = co >> 4;
    int lane = ((k >> 3) & 3) * 16 + (co & 15);
    int e = k & 7;
    size_t o = ((size_t)(t * 16 + cg) * 64 + lane) * 8 + e;
    WtS[o] = bf16_rne(ws[i]);
    WtK[o] = bf16_rne(wk[i]);
}

// ---------------------------------------------------------------------------
// dw_pass8 (search): dw3x3+BN1+ReLU6 -> bf16 plane X3[kc][n][8].
// Double-buffered S; stage(i+1) issued BEFORE compute(i) so the ~2900cy
// HBM delivery hides under compute+scatter+gather (~4000cy). r11-validated
// compute/scatter/gather bodies.
// ---------------------------------------------------------------------------
template<int IN_H, int CG, int NSLICE>
__global__ __launch_bounds__(256)
void dw_pass8(const float* __restrict__ in, const float* __restrict__ dw_w,
              const float* __restrict__ bn1, u16* __restrict__ X3) {
    constexpr int OUT_H = IN_H - 2, ON = OUT_H * OUT_H, IHW = IN_H * IN_H;
    constexpr int NSTRIP = (OUT_H + 7) / 8;
    constexpr int NF4 = CG * IHW / 4;             // 1922
    constexpr int SUBS = CG / 8;                  // 1
    constexpr int NSP = B * ON;
    constexpr int PADC = CG + 2;                  // 10
    __shared__ __align__(16) float S[2][NF4 * 4 + 16];
    __shared__ __align__(16) u16 xt[ON * PADC];

    const int tid = threadIdx.x;
    const int b = blockIdx.x;
    const int g0 = blockIdx.y * NSLICE;

    const bool active = tid < CG * OUT_H;
    int cl = 0, oh = 0;
    if (active) { cl = tid / OUT_H; oh = tid - cl * OUT_H; }

    auto issue_stage = [&](int buf, int g) {
        const float* src = in + ((size_t)b * C + g * CG) * IHW;
        #pragma unroll
        for (int ii = 0; ii < (NF4 + 255) / 256; ++ii) {
            int q = ii * 256 + tid;
            if (q < NF4) GLOAD16(src + q * 4, (char*)S[buf] + q * 16);
        }
    };

    issue_stage(0, g0);
    int cur = 0;

    for (int it = 0; it < NSLICE; ++it) {
        const int g = g0 + it;
        const int ci0 = g * CG;
        asm volatile("s_waitcnt vmcnt(0)" ::: "memory");   // S[cur] delivered
        __syncthreads();                                   // + xt free (prev gather done)

        if (it + 1 < NSLICE) issue_stage(cur ^ 1, g0 + it + 1);  // flies under all below

        // ---- compute from S[cur]
        u16 outv[NSTRIP][8];
        if (active) {
            const int ci = ci0 + cl;
            float wreg[9];
            #pragma unroll
            for (int q = 0; q < 9; ++q) wreg[q] = dw_w[ci * 9 + q];
            const float inv = bn1[ci] * rsqrtf(bn1[3 * C + ci] + EPS);
            const float shv = bn1[C + ci] - bn1[2 * C + ci] * inv;
            #pragma unroll
            for (int s = 0; s < NSTRIP; ++s) {
                float res[8] = {0.f, 0.f, 0.f, 0.f, 0.f, 0.f, 0.f, 0.f};
                #pragma unroll
                for (int dy = 0; dy < 3; ++dy) {
                    const float* r = S[cur] + cl * IHW + (oh + dy) * IN_H + s * 8;
                    float x[10];
                    #pragma unroll
                    for (int j = 0; j < 10; ++j) x[j] = r[j];
                    #pragma unroll
                    for (int o = 0; o < 8; ++o)
                        res[o] = fmaf(x[o], wreg[dy * 3],
                                  fmaf(x[o + 1], wreg[dy * 3 + 1],
                                   fmaf(x[o + 2], wreg[dy * 3 + 2], res[o])));
                }
                #pragma unroll
                for (int o = 0; o < 8; ++o) {
                    float y = res[o] * inv + shv;
                    y = fminf(fmaxf(y, 0.f), 6.f);
                    outv[s][o] = bf16_rne(y);
                }
            }
        }
        __syncthreads();   // compute reads of S[cur] done; xt writable

        if (active) {
            #pragma unroll
            for (int s = 0; s < NSTRIP; ++s) {
                const int ow0 = s * 8;
                #pragma unroll
                for (int o = 0; o < 8; ++o) {
                    if (ow0 + o < OUT_H) {
                        int n = oh * OUT_H + ow0 + o;
                        xt[n * PADC + cl] = outv[s][o];
                    }
                }
            }
        }
        __syncthreads();

        for (int q = tid; q < ON * SUBS; q += 256) {
            int sub = q / ON, n = q - sub * ON;
            const unsigned* w = (const unsigned*)xt + n * (PADC / 2) + sub * 4;
            uint4 v = {w[0], w[1], w[2], w[3]};
            u16* dst = X3 + ((size_t)(g * SUBS + sub) * NSP + (size_t)b * ON + n) * 8;
            *(uint4*)dst = v;
        }
        cur ^= 1;
    }
}

// ---------------------------------------------------------------------------
// dw_pass7 (kernel branch, tiny): unchanged r11 version
// ---------------------------------------------------------------------------
template<int IN_H, int CG>
__global__ __launch_bounds__(256)
void dw_pass7(const float* __restrict__ in, const float* __restrict__ dw_w,
              const float* __restrict__ bn1, u16* __restrict__ X3) {
    constexpr int OUT_H = IN_H - 2, ON = OUT_H * OUT_H, IHW = IN_H * IN_H;
    constexpr int NSTRIP = (OUT_H + 7) / 8;
    constexpr int NFLT = CG * IHW;
    constexpr int NF4 = NFLT / 4;
    constexpr int SUBS = CG / 8;
    constexpr int NSP = B * ON;
    constexpr int PADC = CG + 2;
    constexpr unsigned SM_IN = (NFLT + 16) * 4;
    constexpr unsigned SM_XT = (unsigned)ON * PADC * 2;
    constexpr unsigned SMSZ = SM_IN > SM_XT ? SM_IN : SM_XT;
    __shared__ __align__(16) char SMEM[SMSZ];
    float* S = (float*)SMEM;
    u16* xt = (u16*)SMEM;

    const int tid = threadIdx.x;
    const int b = blockIdx.x, g = blockIdx.y;
    const int ci0 = g * CG;
    const float* src = in + ((size_t)b * C + ci0) * IHW;

    for (int q = tid; q < NF4; q += 256)
        ((float4*)S)[q] = ((const float4*)src)[q];
    __syncthreads();

    const bool active = tid < CG * OUT_H;
    int cl = 0, oh = 0;
    if (active) { cl = tid / OUT_H; oh = tid - cl * OUT_H; }
    u16 outv[NSTRIP][8];
    if (active) {
        const int ci = ci0 + cl;
        float wreg[9];
        #pragma unroll
        for (int q = 0; q < 9; ++q) wreg[q] = dw_w[ci * 9 + q];
        const float inv = bn1[ci] * rsqrtf(bn1[3 * C + ci] + EPS);
        const float shv = bn1[C + ci] - bn1[2 * C + ci] * inv;
        #pragma unroll
        for (int s = 0; s < NSTRIP; ++s) {
            float res[8] = {0.f, 0.f, 0.f, 0.f, 0.f, 0.f, 0.f, 0.f};
            #pragma unroll
            for (int dy = 0; dy < 3; ++dy) {
                const float* r = S + cl * IHW + (oh + dy) * IN_H + s * 8;
                float x[10];
                #pragma unroll
                for (int j = 0; j < 10; ++j) x[j] = r[j];
                #pragma unroll
                for (int o = 0; o < 8; ++o)
                    res[o] = fmaf(x[o], wreg[dy * 3],
                              fmaf(x[o + 1], wreg[dy * 3 + 1],
                               fmaf(x[o + 2], wreg[dy * 3 + 2], res[o])));
            }
            #pragma unroll
            for (int o = 0; o < 8; ++o) {
                float y = res[o] * inv + shv;
                y = fminf(fmaxf(y, 0.f), 6.f);
                outv[s][o] = bf16_rne(y);
            }
        }
    }
    __syncthreads();

    if (active) {
        #pragma unroll
        for (int s = 0; s < NSTRIP; ++s) {
            const int ow0 = s * 8;
            #pragma unroll
            for (int o = 0; o < 8; ++o) {
                if (ow0 + o < OUT_H) {
                    int n = oh * OUT_H + ow0 + o;
                    xt[n * PADC + cl] = outv[s][o];
                }
            }
        }
    }
    __syncthreads();

    for (int q = tid; q < ON * SUBS; q += 256) {
        int sub = q / ON, n = q - sub * ON;
        const unsigned* w = (const unsigned*)xt + n * (PADC / 2) + sub * 4;
        uint4 v = {w[0], w[1], w[2], w[3]};
        u16* dst = X3 + ((size_t)(g * SUBS + sub) * NSP + (size_t)b * ON + n) * 8;
        *(uint4*)dst = v;
    }
}

// ---------------------------------------------------------------------------
// gemm7: LDS-free bf16 MFMA GEMM with register ping-pong prefetch
// (r8 gemm5 macro structure, single plane -> half the buffers, no spill).
// ---------------------------------------------------------------------------
template<int PQ>
__global__ __launch_bounds__(256)
void gemm7(const u16* __restrict__ X3, const u16* __restrict__ Wt,
           const float* __restrict__ pw_b, const float* __restrict__ bn2,
           u16* __restrict__ out) {
    constexpr int NSP = B * PQ;
    const int lane = threadIdx.x & 63, wave = threadIdx.x >> 6;
    const int lh = lane >> 4, ll = lane & 15;
    const int n0 = blockIdx.x * 64;

    f32x4 acc[4][4] = {};
    short8 bx0[4], aw0[4], bx1[4], aw1[4];

#define LOADX(t, bx)                                                            \
    {                                                                           \
        _Pragma("unroll")                                                       \
        for (int j = 0; j < 4; ++j) {                                           \
            size_t off = ((size_t)((t) * 4 + lh) * NSP + n0 + j * 16 + ll) * 8; \
            bx[j] = *(const short8*)(X3 + off);                                 \
        }                                                                       \
    }
#define LOADW(t, aw)                                                            \
    {                                                                           \
        _Pragma("unroll")                                                       \
        for (int i = 0; i < 4; ++i) {                                           \
            size_t off = ((size_t)((t) * 16 + wave * 4 + i) * 64 + lane) * 8;   \
            aw[i] = *(const short8*)(Wt + off);                                 \
        }                                                                       \
    }
#define MM(aw, bx)                                                              \
    {                                                                           \
        _Pragma("unroll")                                                       \
        for (int i = 0; i < 4; ++i) {                                           \
            _Pragma("unroll")                                                   \
            for (int j = 0; j < 4; ++j)                                         \
                acc[i][j] = __builtin_amdgcn_mfma_f32_16x16x32_bf16(aw[i], bx[j], acc[i][j], 0, 0, 0); \
        }                                                                       \
    }

    LOADX(0, bx0); LOADW(0, aw0);
    #pragma unroll
    for (int tt = 0; tt < 8; tt += 2) {
        if (tt + 1 < 8) { LOADX(tt + 1, bx1); LOADW(tt + 1, aw1); }
        MM(aw0, bx0);
        if (tt + 2 < 8) { LOADX(tt + 2, bx0); LOADW(tt + 2, aw0); }
        if (tt + 1 < 8) { MM(aw1, bx1); }
    }
#undef LOADX
#undef LOADW
#undef MM

    int bj[4], pj[4];
    #pragma unroll
    for (int j = 0; j < 4; ++j) {
        int nn = n0 + j * 16 + ll;
        bj[j] = nn / PQ; pj[j] = nn - bj[j] * PQ;
    }
    #pragma unroll
    for (int i = 0; i < 4; ++i) {
        #pragma unroll
        for (int r = 0; r < 4; ++r) {
            int co = wave * 64 + i * 16 + lh * 4 + r;
            float inv = bn2[co] * rsqrtf(bn2[3 * C + co] + EPS);
            float sh  = bn2[C + co] - bn2[2 * C + co] * inv + pw_b[co] * inv;
            #pragma unroll
            for (int j = 0; j < 4; ++j)
                out[((size_t)bj[j] * C + co) * PQ + pj[j]] = bf16_rne(acc[i][j][r] * inv + sh);
        }
    }
}

// ---------------------------------------------------------------------------
// xcorr3: bf16 inputs, fp32 output (r11-validated).
// ---------------------------------------------------------------------------
__global__ __launch_bounds__(256)
void xcorr3(const u16* __restrict__ s, const u16* __restrict__ k,
            float* __restrict__ out) {
    const int bc0 = blockIdx.x * 10;
    const int nbc = min(10, B * C - bc0);
    __shared__ float ss[10 * 841];
    __shared__ float ks[10 * 25];
    const int tid = threadIdx.x;
    for (int i = tid; i < nbc * 841; i += 256) ss[i] = bf16_f(s[(size_t)bc0 * 841 + i]);
    for (int i = tid; i < nbc * 25; i += 256) ks[i] = bf16_f(k[(size_t)bc0 * 25 + i]);
    __syncthreads();

    const int lb = tid / 25, lt = tid - lb * 25;
    if (lb >= nbc) return;
    const int ohg = lt / 5, owg = lt - ohg * 5;
    const float* sp = ss + lb * 841 + (ohg * 5) * 29 + owg * 5;
    float kk[25];
    #pragma unroll
    for (int q = 0; q < 25; ++q) kk[q] = ks[lb * 25 + q];

    float acc[5][5] = {};
    #pragma unroll
    for (int ir = 0; ir < 9; ++ir) {
        float row[9];
        #pragma unroll
        for (int j = 0; j < 9; ++j) row[j] = sp[ir * 29 + j];
        #pragma unroll
        for (int oi = 0; oi < 5; ++oi) {
            int ki = ir - oi;
            if (ki < 0 || ki > 4) continue;
            #pragma unroll
            for (int oj = 0; oj < 5; ++oj)
                #pragma unroll
                for (int kj = 0; kj < 5; ++kj)
                    acc[oi][oj] = fmaf(row[oj + kj], kk[ki * 5 + kj], acc[oi][oj]);
        }
    }
    float* op = out + (size_t)(bc0 + lb) * 625;
    #pragma unroll
    for (int oi = 0; oi < 5; ++oi)
        #pragma unroll
        for (int oj = 0; oj < 5; ++oj)
            op[(ohg * 5 + oi) * 25 + owg * 5 + oj] = acc[oi][oj];
}

// ---------------------------------------------------------------------------
// Fallback (round-1 fp32 path) in case ws_size is too small
// ---------------------------------------------------------------------------
template<int IN_H>
__global__ __launch_bounds__(256)
void branch_fallback(const float* __restrict__ in, const float* __restrict__ dw_w,
                     const float* __restrict__ bn1, const float* __restrict__ pw_w,
                     const float* __restrict__ pw_b, const float* __restrict__ bn2,
                     float* __restrict__ out) {
    constexpr int OUT_H = IN_H - 2;
    constexpr int P = OUT_H * OUT_H;
    const int n0  = blockIdx.x * 64;
    const int co0 = blockIdx.y * 64;
    const int tid = threadIdx.x;
    const int tx = tid & 15, ty = tid >> 4;
    __shared__ __align__(16) float Ws[16][64];
    __shared__ __align__(16) float Xs2[16][64];
    float acc[4][4] = {};
    for (int k0 = 0; k0 < C; k0 += 16) {
        #pragma unroll
        for (int e = 0; e < 4; e++) {
            int idx = e * 256 + tid;
            int m = idx & 63, kk = idx >> 6;
            Ws[kk][m] = pw_w[(co0 + m) * C + (k0 + kk)];
        }
        #pragma unroll
        for (int e = 0; e < 4; e++) {
            int idx = e * 256 + tid;
            int nn = idx & 63, kk = idx >> 6;
            int ci = k0 + kk;
            int n = n0 + nn;
            int b = n / P, p = n - b * P;
            int oh = p / OUT_H, ow = p - oh * OUT_H;
            const float* ip = in + (((size_t)b * C + ci) * IN_H + oh) * IN_H + ow;
            const float* wp = dw_w + ci * 9;
            float s = 0.f;
            #pragma unroll
            for (int dy = 0; dy < 3; dy++)
                #pragma unroll
                for (int dx = 0; dx < 3; dx++)
                    s = fmaf(ip[dy * IN_H + dx], wp[dy * 3 + dx], s);
            float inv = bn1[ci] * rsqrtf(bn1[3 * C + ci] + EPS);
            float y = s * inv + (bn1[C + ci] - bn1[2 * C + ci] * inv);
            Xs2[kk][nn] = fminf(fmaxf(y, 0.f), 6.f);
        }
        __syncthreads();
        #pragma unroll
        for (int kk = 0; kk < 16; kk++) {
            float4 av = *reinterpret_cast<const float4*>(&Ws[kk][ty * 4]);
            float4 bv = *reinterpret_cast<const float4*>(&Xs2[kk][tx * 4]);
            float a[4] = {av.x, av.y, av.z, av.w};
            float bb[4] = {bv.x, bv.y, bv.z, bv.w};
            #pragma unroll
            for (int i = 0; i < 4; i++)
                #pragma unroll
                for (int j = 0; j < 4; j++)
                    acc[i][j] = fmaf(a[i], bb[j], acc[i][j]);
        }
        __syncthreads();
    }
    #pragma unroll
    for (int i = 0; i < 4; i++) {
        int co = co0 + ty * 4 + i;
        float inv = bn2[co] * rsqrtf(bn2[3 * C + co] + EPS);
        float sh  = (bn2[C + co] - bn2[2 * C + co] * inv) + pw_b[co] * inv;
        int n = n0 + tx * 4;
        #pragma unroll
        for (int j = 0; j < 4; j++) {
            int nj = n + j;
            int bj2 = nj / P, pj2 = nj - bj2 * P;
            out[((size_t)bj2 * C + co) * P + pj2] = acc[i][j] * inv + sh;
        }
    }
}

__global__ __launch_bounds__(256)
void xcorr2f(const float* __restrict__ s, const float* __restrict__ k,
             float* __restrict__ out) {
    const int bc0 = blockIdx.x * 10;
    const int nbc = min(10, B * C - bc0);
    __shared__ float ss[10 * 841];
    __shared__ float ks[10 * 25];
    const int tid = threadIdx.x;
    for (int i = tid; i < nbc * 841; i += 256) ss[i] = s[(size_t)bc0 * 841 + i];
    for (int i = tid; i < nbc * 25; i += 256) ks[i] = k[(size_t)bc0 * 25 + i];
    __syncthreads();
    const int lb = tid / 25, lt = tid - lb * 25;
    if (lb >= nbc) return;
    const int ohg = lt / 5, owg = lt - ohg * 5;
    const float* sp = ss + lb * 841 + (ohg * 5) * 29 + owg * 5;
    float kk[25];
    #pragma unroll
    for (int q = 0; q < 25; ++q) kk[q] = ks[lb * 25 + q];
    float acc[5][5] = {};
    #pragma unroll
    for (int ir = 0; ir < 9; ++ir) {
        float row[9];
        #pragma unroll
        for (int j = 0; j < 9; ++j) row[j] = sp[ir * 29 + j];
        #pragma unroll
        for (int oi = 0; oi < 5; ++oi) {
            int ki = ir - oi;
            if (ki < 0 || ki > 4) continue;
            #pragma unroll
            for (int oj = 0; oj < 5; ++oj)
                #pragma unroll
                for (int kj = 0; kj < 5; ++kj)
                    acc[oi][oj] = fmaf(row[oj + kj], kk[ki * 5 + kj], acc[oi][oj]);
        }
    }
    float* op = out + (size_t)(bc0 + lb) * 625;
    #pragma unroll
    for (int oi = 0; oi < 5; ++oi)
        #pragma unroll
        for (int oj = 0; oj < 5; ++oj)
            op[(ohg * 5 + oi) * 25 + owg * 5 + oj] = acc[oi][oj];
}

extern "C" void kernel_launch(void* const* d_in, const int* in_sizes, int n_in,
                              void* d_out, int out_size, void* d_ws, size_t ws_size,
                              hipStream_t stream) {
    const float* kernel = (const float*)d_in[0];
    const float* search = (const float*)d_in[1];
    const float* k_dw_w = (const float*)d_in[2];
    const float* k_bn1  = (const float*)d_in[3];
    const float* k_pw_w = (const float*)d_in[4];
    const float* k_pw_b = (const float*)d_in[5];
    const float* k_bn2  = (const float*)d_in[6];
    const float* s_dw_w = (const float*)d_in[7];
    const float* s_bn1  = (const float*)d_in[8];
    const float* s_pw_w = (const float*)d_in[9];
    const float* s_pw_b = (const float*)d_in[10];
    const float* s_bn2  = (const float*)d_in[11];

    constexpr size_t SB_B  = (size_t)NSG * C * 2;      // 55,115,776 (bf16)
    constexpr size_t KB_B  = (size_t)NKG * C * 2;      //  1,638,400
    constexpr size_t X3S_B = (size_t)NSG * C * 2;      // 55,115,776
    constexpr size_t X3K_B = (size_t)NKG * C * 2;      //  1,638,400
    constexpr size_t W_B   = (size_t)C * C * 2;        //    131,072 per branch
    constexpr size_t NEED  = SB_B + KB_B + X3S_B + X3K_B + 2 * W_B;

    if (ws_size >= NEED) {
        char* base = (char*)d_ws;
        u16* Sb   = (u16*)base;   base += SB_B;
        u16* Kb   = (u16*)base;   base += KB_B;
        u16* X3s  = (u16*)base;   base += X3S_B;
        u16* X3k  = (u16*)base;   base += X3K_B;
        u16* WtS  = (u16*)base;   base += W_B;
        u16* WtK  = (u16*)base;

        wprep3<<<dim3(256), dim3(256), 0, stream>>>(s_pw_w, k_pw_w, WtS, WtK);
        dw_pass8<31, 8, 4><<<dim3(B, 8), dim3(256), 0, stream>>>(search, s_dw_w, s_bn1, X3s);
        dw_pass7<7, 32><<<dim3(B, 8), dim3(256), 0, stream>>>(kernel, k_dw_w, k_bn1, X3k);
        gemm7<841><<<dim3(NSG / 64), dim3(256), 0, stream>>>(X3s, WtS, s_pw_b, s_bn2, Sb);
        gemm7<25><<<dim3(NKG / 64), dim3(256), 0, stream>>>(X3k, WtK, k_pw_b, k_bn2, Kb);
        xcorr3<<<dim3((B * C + 9) / 10), dim3(256), 0, stream>>>(Sb, Kb, (float*)d_out);
    } else {
        float* s_buf = (float*)d_ws;
        float* k_buf = s_buf + (size_t)B * C * 29 * 29;
        branch_fallback<7><<<dim3(50, 4), dim3(256), 0, stream>>>(
            kernel, k_dw_w, k_bn1, k_pw_w, k_pw_b, k_bn2, k_buf);
        branch_fallback<31><<<dim3(1682, 4), dim3(256), 0, stream>>>(
            search, s_dw_w, s_bn1, s_pw_w, s_pw_b, s_bn2, s_buf);
        xcorr2f<<<dim3((B * C + 9) / 10), dim3(256), 0, stream>>>(s_buf, k_buf, (float*)d_out);
    }
}